// Round 1
// baseline (3175.158 us; speedup 1.0000x reference)
//
#include <hip/hip_runtime.h>

// Problem constants: B=8, L=512, N=64, D=1024
constexpr int Bb   = 8;
constexpr int Lseq = 512;
constexpr int Nsp  = 64;
constexpr int Dm   = 1024;   // D
constexpr int D2   = 2048;   // 2D

// ---------------------------------------------------------------------------
// Gather h rows at span start/end indices.
// grid: (512, 2) blocks, 256 threads. Each block copies one 1024-float row.
// ---------------------------------------------------------------------------
__global__ __launch_bounds__(256)
void gather_rows(const float* __restrict__ h, const int* __restrict__ span,
                 float* __restrict__ gs, float* __restrict__ ge)
{
    const int row   = blockIdx.x;    // b*64 + n, 0..511
    const int which = blockIdx.y;    // 0 = start, 1 = end
    const int b     = row >> 6;
    const int idx   = span[row * 2 + which];
    const float4* src = (const float4*)(h + ((size_t)b * Lseq + idx) * Dm);
    float4* dst = (float4*)((which ? ge : gs) + (size_t)row * Dm);
    dst[threadIdx.x] = src[threadIdx.x];   // 256 * 16B = 4096B = 1024 floats
}

// ---------------------------------------------------------------------------
// Generic fp32 GEMM: C[M x N] = act(A[M x K] @ W[K x N] + bias)
// BM=BN=64, BK=16, 256 threads, 4x4 accum per thread. M,N %64==0, K %16==0.
// ---------------------------------------------------------------------------
template<bool RELU, bool BIAS>
__global__ __launch_bounds__(256)
void gemm_f32(const float* __restrict__ A, int lda,
              const float* __restrict__ W, int ldw,
              const float* __restrict__ bias,
              float* __restrict__ C, int ldc,
              int K)
{
    __shared__ float As[16][64];   // As[k][m]
    __shared__ float Ws[16][64];   // Ws[k][n]

    const int tid = threadIdx.x;
    const int tx  = tid & 15;      // -> 4 cols
    const int ty  = tid >> 4;      // -> 4 rows
    const int m0  = blockIdx.x * 64;
    const int n0  = blockIdx.y * 64;

    const int la_c = tid & 15;     // k within A tile
    const int la_r = tid >> 4;     // m base within A tile
    const int lw_n = tid & 63;     // n within W tile
    const int lw_k = tid >> 6;     // k base within W tile

    float acc[4][4] = {};

    for (int k0 = 0; k0 < K; k0 += 16) {
#pragma unroll
        for (int s = 0; s < 4; ++s) {
            int m = la_r + 16 * s;
            As[la_c][m] = A[(size_t)(m0 + m) * lda + k0 + la_c];
        }
#pragma unroll
        for (int s = 0; s < 4; ++s) {
            int k = lw_k + 4 * s;
            Ws[k][lw_n] = W[(size_t)(k0 + k) * ldw + n0 + lw_n];
        }
        __syncthreads();
#pragma unroll
        for (int kk = 0; kk < 16; ++kk) {
            float a4[4], w4[4];
            *(float4*)a4 = *(const float4*)&As[kk][ty * 4];
            *(float4*)w4 = *(const float4*)&Ws[kk][tx * 4];
#pragma unroll
            for (int i = 0; i < 4; ++i)
#pragma unroll
                for (int j = 0; j < 4; ++j)
                    acc[i][j] = fmaf(a4[i], w4[j], acc[i][j]);
        }
        __syncthreads();
    }

#pragma unroll
    for (int i = 0; i < 4; ++i) {
        float4 v;
        float* vp = (float*)&v;
#pragma unroll
        for (int j = 0; j < 4; ++j) {
            float x = acc[i][j];
            if (BIAS) x += bias[n0 + tx * 4 + j];
            if (RELU) x = fmaxf(x, 0.f);
            vp[j] = x;
        }
        *(float4*)&C[(size_t)(m0 + ty * 4 + i) * ldc + n0 + tx * 4] = v;
    }
}

// ---------------------------------------------------------------------------
// Final GEMM: out[b,i,j,:] = relu(hi[b,i,:] + hj[b,j,:] + br1) @ Wr2 + br2
// hidden never materialized: A-tile built on the fly in LDS.
// grid: (512 = b*64+i, 16 = n-tiles of 64), 256 threads, 64x64x16 tiling.
// ---------------------------------------------------------------------------
__global__ __launch_bounds__(256)
void big_gemm(const float* __restrict__ hi, const float* __restrict__ hj,
              const float* __restrict__ br1, const float* __restrict__ Wr2,
              const float* __restrict__ br2, float* __restrict__ out)
{
    __shared__ float As[16][64];   // As[k][j]  (M-dim within tile = j)
    __shared__ float Ws[16][64];

    const int tid = threadIdx.x;
    const int tx  = tid & 15;
    const int ty  = tid >> 4;
    const int bi  = blockIdx.x;          // b*64 + i
    const int b   = bi >> 6;
    const int n0  = blockIdx.y * 64;

    const float* hi_row   = hi + (size_t)bi * D2;
    const float* hj_base  = hj + (size_t)b * Nsp * D2;

    const int la_c = tid & 15;
    const int la_r = tid >> 4;
    const int lw_n = tid & 63;
    const int lw_k = tid >> 6;

    float acc[4][4] = {};

    for (int k0 = 0; k0 < D2; k0 += 16) {
        const float hiv = hi_row[k0 + la_c] + br1[k0 + la_c];
#pragma unroll
        for (int s = 0; s < 4; ++s) {
            int j = la_r + 16 * s;
            As[la_c][j] = fmaxf(hiv + hj_base[(size_t)j * D2 + k0 + la_c], 0.f);
        }
#pragma unroll
        for (int s = 0; s < 4; ++s) {
            int k = lw_k + 4 * s;
            Ws[k][lw_n] = Wr2[(size_t)(k0 + k) * Dm + n0 + lw_n];
        }
        __syncthreads();
#pragma unroll
        for (int kk = 0; kk < 16; ++kk) {
            float a4[4], w4[4];
            *(float4*)a4 = *(const float4*)&As[kk][ty * 4];
            *(float4*)w4 = *(const float4*)&Ws[kk][tx * 4];
#pragma unroll
            for (int i = 0; i < 4; ++i)
#pragma unroll
                for (int j = 0; j < 4; ++j)
                    acc[i][j] = fmaf(a4[i], w4[j], acc[i][j]);
        }
        __syncthreads();
    }

#pragma unroll
    for (int i = 0; i < 4; ++i) {
        const int j = ty * 4 + i;  // row within tile = span index j
        float4 v;
        float* vp = (float*)&v;
#pragma unroll
        for (int jj = 0; jj < 4; ++jj)
            vp[jj] = acc[i][jj] + br2[n0 + tx * 4 + jj];
        *(float4*)&out[((size_t)bi * Nsp + j) * Dm + n0 + tx * 4] = v;
    }
}

// ---------------------------------------------------------------------------
extern "C" void kernel_launch(void* const* d_in, const int* in_sizes, int n_in,
                              void* d_out, int out_size, void* d_ws, size_t ws_size,
                              hipStream_t stream) {
    const float* h    = (const float*)d_in[0];
    const int*   span = (const int*)  d_in[1];
    const float* Ws1  = (const float*)d_in[2];
    const float* bs1  = (const float*)d_in[3];
    const float* Ws2  = (const float*)d_in[4];
    const float* bs2  = (const float*)d_in[5];
    const float* We1  = (const float*)d_in[6];
    const float* be1  = (const float*)d_in[7];
    const float* We2  = (const float*)d_in[8];
    const float* be2  = (const float*)d_in[9];
    const float* Wo   = (const float*)d_in[10];
    const float* bo   = (const float*)d_in[11];
    const float* Wr1  = (const float*)d_in[12];
    const float* br1  = (const float*)d_in[13];
    const float* Wr2  = (const float*)d_in[14];
    const float* br2  = (const float*)d_in[15];
    float* out = (float*)d_out;

    // Workspace layout (floats). Total = 5.77M floats = 23.1 MiB.
    float* ws  = (float*)d_ws;
    float* gs  = ws;                       // 512*1024 gathered start rows
    float* ge  = gs  + 512 * Dm;           // 512*1024 gathered end rows
    float* t1  = ge  + 512 * Dm;           // 512*2048 MLP hidden (reused)
    float* cat = t1  + 512 * D2;           // 512*2048 relu(concat)
    float* ent = cat + 512 * D2;           // 512*2048 entity_reps
    float* hi  = ent + 512 * D2;           // 512*2048
    float* hj  = hi  + 512 * D2;           // 512*2048

    dim3 blk(256);

    gather_rows<<<dim3(512, 2), blk, 0, stream>>>(h, span, gs, ge);

    // start branch: relu(gs@Ws1+bs1) @ Ws2 + bs2 -> relu -> cat[:, :1024]
    gemm_f32<true,  true><<<dim3(8, 32), blk, 0, stream>>>(gs, Dm, Ws1, D2, bs1, t1, D2, Dm);
    gemm_f32<true,  true><<<dim3(8, 16), blk, 0, stream>>>(t1, D2, Ws2, Dm, bs2, cat, D2, D2);
    // end branch -> cat[:, 1024:]
    gemm_f32<true,  true><<<dim3(8, 32), blk, 0, stream>>>(ge, Dm, We1, D2, be1, t1, D2, Dm);
    gemm_f32<true,  true><<<dim3(8, 16), blk, 0, stream>>>(t1, D2, We2, Dm, be2, cat + Dm, D2, D2);
    // entity = cat @ Wo + bo
    gemm_f32<false, true><<<dim3(8, 32), blk, 0, stream>>>(cat, D2, Wo, D2, bo, ent, D2, D2);
    // hi = ent @ Wr1[:2048], hj = ent @ Wr1[2048:]
    gemm_f32<false, false><<<dim3(8, 32), blk, 0, stream>>>(ent, D2, Wr1, D2, nullptr, hi, D2, D2);
    gemm_f32<false, false><<<dim3(8, 32), blk, 0, stream>>>(ent, D2, Wr1 + (size_t)D2 * D2, D2, nullptr, hj, D2, D2);
    // out = relu(hi ⊕ hj + br1) @ Wr2 + br2
    big_gemm<<<dim3(512, 16), blk, 0, stream>>>(hi, hj, br1, Wr2, br2, out);
}

// Round 2
// 1177.475 us; speedup vs baseline: 2.6966x; 2.6966x over previous
//
#include <hip/hip_runtime.h>

// Problem constants: B=8, L=512, N=64, D=1024
constexpr int Bb   = 8;
constexpr int Lseq = 512;
constexpr int Nsp  = 64;
constexpr int Dm   = 1024;   // D
constexpr int D2   = 2048;   // 2D

typedef __attribute__((ext_vector_type(8))) short short8;
typedef __attribute__((ext_vector_type(4))) float floatx4;

__device__ __forceinline__ unsigned int f2bf(float x) {
    unsigned int u = __float_as_uint(x);
    return (u + 0x7fffu + ((u >> 16) & 1u)) >> 16;   // RNE
}

// ---------------------------------------------------------------------------
// Gather h rows at span start/end indices.
// ---------------------------------------------------------------------------
__global__ __launch_bounds__(256)
void gather_rows(const float* __restrict__ h, const int* __restrict__ span,
                 float* __restrict__ gs, float* __restrict__ ge)
{
    const int row   = blockIdx.x;    // b*64 + n
    const int which = blockIdx.y;
    const int b     = row >> 6;
    const int idx   = span[row * 2 + which];
    const float4* src = (const float4*)(h + ((size_t)b * Lseq + idx) * Dm);
    float4* dst = (float4*)((which ? ge : gs) + (size_t)row * Dm);
    dst[threadIdx.x] = src[threadIdx.x];
}

// ---------------------------------------------------------------------------
// Transpose+convert Wr2[k][n] fp32 -> Wt[n][k] bf16. grid (32,16), one-time.
// ---------------------------------------------------------------------------
__global__ __launch_bounds__(256)
void transpose_wr2(const float* __restrict__ Wr2, unsigned short* __restrict__ Wt)
{
    __shared__ float T[64][65];
    const int k0 = blockIdx.x * 64, n0 = blockIdx.y * 64;
    const int t = threadIdx.x;
    const int c = t & 63, r4 = t >> 6;
#pragma unroll
    for (int s = 0; s < 16; ++s) {
        int r = r4 * 16 + s;
        T[r][c] = Wr2[(size_t)(k0 + r) * Dm + n0 + c];
    }
    __syncthreads();
#pragma unroll
    for (int s = 0; s < 16; ++s) {
        int n = r4 * 16 + s;
        Wt[(size_t)(n0 + n) * D2 + k0 + c] = (unsigned short)f2bf(T[c][n]);
    }
}

// ---------------------------------------------------------------------------
// Generic fp32 GEMM (unchanged baseline) for the small projection layers.
// ---------------------------------------------------------------------------
template<bool RELU, bool BIAS>
__global__ __launch_bounds__(256)
void gemm_f32(const float* __restrict__ A, int lda,
              const float* __restrict__ W, int ldw,
              const float* __restrict__ bias,
              float* __restrict__ C, int ldc,
              int K)
{
    __shared__ float As[16][64];
    __shared__ float Ws[16][64];

    const int tid = threadIdx.x;
    const int tx  = tid & 15;
    const int ty  = tid >> 4;
    const int m0  = blockIdx.x * 64;
    const int n0  = blockIdx.y * 64;

    const int la_c = tid & 15;
    const int la_r = tid >> 4;
    const int lw_n = tid & 63;
    const int lw_k = tid >> 6;

    float acc[4][4] = {};

    for (int k0 = 0; k0 < K; k0 += 16) {
#pragma unroll
        for (int s = 0; s < 4; ++s) {
            int m = la_r + 16 * s;
            As[la_c][m] = A[(size_t)(m0 + m) * lda + k0 + la_c];
        }
#pragma unroll
        for (int s = 0; s < 4; ++s) {
            int k = lw_k + 4 * s;
            Ws[k][lw_n] = W[(size_t)(k0 + k) * ldw + n0 + lw_n];
        }
        __syncthreads();
#pragma unroll
        for (int kk = 0; kk < 16; ++kk) {
            float a4[4], w4[4];
            *(float4*)a4 = *(const float4*)&As[kk][ty * 4];
            *(float4*)w4 = *(const float4*)&Ws[kk][tx * 4];
#pragma unroll
            for (int i = 0; i < 4; ++i)
#pragma unroll
                for (int j = 0; j < 4; ++j)
                    acc[i][j] = fmaf(a4[i], w4[j], acc[i][j]);
        }
        __syncthreads();
    }

#pragma unroll
    for (int i = 0; i < 4; ++i) {
        float4 v;
        float* vp = (float*)&v;
#pragma unroll
        for (int j = 0; j < 4; ++j) {
            float x = acc[i][j];
            if (BIAS) x += bias[n0 + tx * 4 + j];
            if (RELU) x = fmaxf(x, 0.f);
            vp[j] = x;
        }
        *(float4*)&C[(size_t)(m0 + ty * 4 + i) * ldc + n0 + tx * 4] = v;
    }
}

// ---------------------------------------------------------------------------
// Final GEMM via bf16 MFMA, hidden built on-the-fly.
// out[bi, j, n] = relu(hi[bi,:] + hj[b*64+j,:] + br1) @ Wr2 + br2
// Block: 2 bi rows (M=128) x 128 N-cols. 256 thr = 4 waves, each 64x64.
// grid (256, 8).
// ---------------------------------------------------------------------------
__global__ __launch_bounds__(256, 3)
void big_mfma(const float* __restrict__ hi, const float* __restrict__ hj,
              const float* __restrict__ br1, const unsigned short* __restrict__ Wt,
              const float* __restrict__ br2, float* __restrict__ out)
{
    __shared__ float hiP[2][D2];                         // hi+br1 for both rows, 16 KB
    __shared__ __align__(16) unsigned short Asb[128 * 32]; // A tile [m][k] bf16, 8 KB
    __shared__ __align__(16) unsigned short Bsb[128 * 32]; // B tile [n][k] bf16, 8 KB

    const int tid = threadIdx.x;
    const int p   = blockIdx.x;          // bi pair index
    const int n0  = blockIdx.y * 128;
    const int b   = p >> 5;
    const int bi0 = p * 2;

    // ---- hiP = hi(+pair) + br1 ----
    {
        const float4* h0 = (const float4*)(hi + (size_t)bi0 * D2);
        const float4* h1 = (const float4*)(hi + (size_t)(bi0 + 1) * D2);
        const float4* br = (const float4*)br1;
        float4* d0 = (float4*)hiP[0];
        float4* d1 = (float4*)hiP[1];
        for (int v = tid; v < 512; v += 256) {
            float4 bb = br[v];
            float4 a = h0[v];
            a.x += bb.x; a.y += bb.y; a.z += bb.z; a.w += bb.w;
            d0[v] = a;
            float4 c = h1[v];
            c.x += bb.x; c.y += bb.y; c.z += bb.z; c.w += bb.w;
            d1[v] = c;
        }
    }

    // A-build mapping: thread covers row am, k-half akh (16 elems = 32B)
    const int am  = tid >> 1;
    const int akh = tid & 1;
    const int asel = am >> 6;
    const int aj   = am & 63;
    const float* hjrow = hj + ((size_t)b * 64 + aj) * D2 + akh * 16;

    const int w  = tid >> 6;             // wave id
    const int l  = tid & 63;             // lane
    const int wm = w & 1, wn = w >> 1;   // wave tile: M-half, N-half
    const int lr = l & 15, lq = l >> 4;  // row-in-tile, quad

    floatx4 acc[4][4];
#pragma unroll
    for (int mt = 0; mt < 4; ++mt)
#pragma unroll
        for (int nt = 0; nt < 4; ++nt)
            acc[mt][nt] = (floatx4){0.f, 0.f, 0.f, 0.f};

    for (int k0 = 0; k0 < D2; k0 += 32) {
        __syncthreads();   // prev frag reads done (and hiP ready on iter 0)

        // ---- A tile: relu(hi' + hj) -> bf16 ----
        {
            const float4* hjp = (const float4*)(hjrow + k0);
            const float4* hkp = (const float4*)&hiP[asel][k0 + akh * 16];
            float4 jv[4], hv[4];
#pragma unroll
            for (int q = 0; q < 4; ++q) { jv[q] = hjp[q]; hv[q] = hkp[q]; }
            unsigned int pk[8];
#pragma unroll
            for (int q = 0; q < 4; ++q) {
                float x0 = fmaxf(jv[q].x + hv[q].x, 0.f);
                float x1 = fmaxf(jv[q].y + hv[q].y, 0.f);
                float x2 = fmaxf(jv[q].z + hv[q].z, 0.f);
                float x3 = fmaxf(jv[q].w + hv[q].w, 0.f);
                pk[q * 2]     = (f2bf(x1) << 16) | f2bf(x0);
                pk[q * 2 + 1] = (f2bf(x3) << 16) | f2bf(x2);
            }
            uint4* aw = (uint4*)&Asb[am * 32 + akh * 16];
            aw[0] = make_uint4(pk[0], pk[1], pk[2], pk[3]);
            aw[1] = make_uint4(pk[4], pk[5], pk[6], pk[7]);
        }

        // ---- B tile: async bf16 stage, lane-contiguous ----
#pragma unroll
        for (int c = 0; c < 2; ++c) {
            const unsigned short* g = Wt + (size_t)(n0 + w * 32 + c * 16 + (l >> 2)) * D2
                                        + k0 + (l & 3) * 8;
            unsigned short* lp = Bsb + (w * 2048 + c * 1024) / 2;  // wave-uniform base
            __builtin_amdgcn_global_load_lds(
                (const __attribute__((address_space(1))) unsigned int*)g,
                (__attribute__((address_space(3))) unsigned int*)lp, 16, 0, 0);
        }

        __syncthreads();   // staging visible

        // ---- fragments + MFMA ----
        short8 af[4], bfr[4];
#pragma unroll
        for (int mt = 0; mt < 4; ++mt)
            af[mt] = *(const short8*)&Asb[(wm * 64 + mt * 16 + lr) * 32 + lq * 8];
#pragma unroll
        for (int nt = 0; nt < 4; ++nt)
            bfr[nt] = *(const short8*)&Bsb[(wn * 64 + nt * 16 + lr) * 32 + lq * 8];
#pragma unroll
        for (int mt = 0; mt < 4; ++mt)
#pragma unroll
            for (int nt = 0; nt < 4; ++nt)
                acc[mt][nt] = __builtin_amdgcn_mfma_f32_16x16x32_bf16(
                    af[mt], bfr[nt], acc[mt][nt], 0, 0, 0);
    }

    // ---- epilogue: + br2, store ----
    float bias[4];
#pragma unroll
    for (int nt = 0; nt < 4; ++nt)
        bias[nt] = br2[n0 + wn * 64 + nt * 16 + lr];

#pragma unroll
    for (int mt = 0; mt < 4; ++mt) {
        const int mbase = wm * 64 + mt * 16 + lq * 4;
#pragma unroll
        for (int r = 0; r < 4; ++r) {
            const int mm  = mbase + r;
            const int sel = mm >> 6, j = mm & 63;
            float* orow = out + (((size_t)(bi0 + sel) * 64 + j) * Dm) + n0 + wn * 64;
#pragma unroll
            for (int nt = 0; nt < 4; ++nt)
                orow[nt * 16 + lr] = acc[mt][nt][r] + bias[nt];
        }
    }
}

// ---------------------------------------------------------------------------
extern "C" void kernel_launch(void* const* d_in, const int* in_sizes, int n_in,
                              void* d_out, int out_size, void* d_ws, size_t ws_size,
                              hipStream_t stream) {
    const float* h    = (const float*)d_in[0];
    const int*   span = (const int*)  d_in[1];
    const float* Ws1  = (const float*)d_in[2];
    const float* bs1  = (const float*)d_in[3];
    const float* Ws2  = (const float*)d_in[4];
    const float* bs2  = (const float*)d_in[5];
    const float* We1  = (const float*)d_in[6];
    const float* be1  = (const float*)d_in[7];
    const float* We2  = (const float*)d_in[8];
    const float* be2  = (const float*)d_in[9];
    const float* Wo   = (const float*)d_in[10];
    const float* bo   = (const float*)d_in[11];
    const float* Wr1  = (const float*)d_in[12];
    const float* br1  = (const float*)d_in[13];
    const float* Wr2  = (const float*)d_in[14];
    const float* br2  = (const float*)d_in[15];
    float* out = (float*)d_out;

    // Workspace layout
    unsigned short* Wt = (unsigned short*)d_ws;          // 1024*2048 bf16 = 4 MB
    float* ws  = (float*)((char*)d_ws + (size_t)Dm * D2 * 2);
    float* gs  = ws;                       // 512*1024
    float* ge  = gs  + 512 * Dm;           // 512*1024
    float* t1  = ge  + 512 * Dm;           // 512*2048
    float* cat = t1  + 512 * D2;           // 512*2048
    float* ent = cat + 512 * D2;           // 512*2048
    float* hi  = ent + 512 * D2;           // 512*2048
    float* hj  = hi  + 512 * D2;           // 512*2048

    dim3 blk(256);

    transpose_wr2<<<dim3(32, 16), blk, 0, stream>>>(Wr2, Wt);
    gather_rows<<<dim3(512, 2), blk, 0, stream>>>(h, span, gs, ge);

    gemm_f32<true,  true><<<dim3(8, 32), blk, 0, stream>>>(gs, Dm, Ws1, D2, bs1, t1, D2, Dm);
    gemm_f32<true,  true><<<dim3(8, 16), blk, 0, stream>>>(t1, D2, Ws2, Dm, bs2, cat, D2, D2);
    gemm_f32<true,  true><<<dim3(8, 32), blk, 0, stream>>>(ge, Dm, We1, D2, be1, t1, D2, Dm);
    gemm_f32<true,  true><<<dim3(8, 16), blk, 0, stream>>>(t1, D2, We2, Dm, be2, cat + Dm, D2, D2);
    gemm_f32<false, true><<<dim3(8, 32), blk, 0, stream>>>(cat, D2, Wo, D2, bo, ent, D2, D2);
    gemm_f32<false, false><<<dim3(8, 32), blk, 0, stream>>>(ent, D2, Wr1, D2, nullptr, hi, D2, D2);
    gemm_f32<false, false><<<dim3(8, 32), blk, 0, stream>>>(ent, D2, Wr1 + (size_t)D2 * D2, D2, nullptr, hj, D2, D2);

    big_mfma<<<dim3(256, 8), blk, 0, stream>>>(hi, hj, br1, Wt, br2, out);
}

// Round 3
// 557.979 us; speedup vs baseline: 5.6905x; 2.1103x over previous
//
#include <hip/hip_runtime.h>
#include <hip/hip_bf16.h>

// Problem constants: B=8, L=512, N=64, D=1024
constexpr int Lseq = 512;
constexpr int Nsp  = 64;
constexpr int Dm   = 1024;   // D
constexpr int D2   = 2048;   // 2D

typedef __attribute__((ext_vector_type(8))) short short8;
typedef __attribute__((ext_vector_type(4))) float floatx4;
typedef unsigned short u16;
typedef unsigned int   u32;

__device__ __forceinline__ u32 f2bf(float x) {
    u32 u = __float_as_uint(x);
    return (u + 0x7fffu + ((u >> 16) & 1u)) >> 16;   // RNE
}
__device__ __forceinline__ float bf2f(u32 hbits) {
    return __uint_as_float(hbits << 16);
}
__device__ __forceinline__ u32 pk2(float x0, float x1) {
    __hip_bfloat162 bb = __float22bfloat162_rn(make_float2(x0, x1));
    u32 r; __builtin_memcpy(&r, &bb, 4); return r;
}

// ---------------------------------------------------------------------------
// Gather h rows at span indices, emitting hi/lo bf16 split. grid (512,2).
// ---------------------------------------------------------------------------
__global__ __launch_bounds__(256)
void gather_split(const float* __restrict__ h, const int* __restrict__ span,
                  u16* __restrict__ g_hi, u16* __restrict__ g_lo)
{
    const int row = blockIdx.x, which = blockIdx.y;
    const int b = row >> 6;
    const int idx = span[row * 2 + which];
    const float4* src = (const float4*)(h + ((size_t)b * Lseq + idx) * Dm);
    float4 v = src[threadIdx.x];
    u32 h01 = pk2(v.x, v.y), h23 = pk2(v.z, v.w);
    u32 l01 = pk2(v.x - bf2f(h01 & 0xffffu), v.y - bf2f(h01 >> 16));
    u32 l23 = pk2(v.z - bf2f(h23 & 0xffffu), v.w - bf2f(h23 >> 16));
    size_t off = ((size_t)which * 512 + row) * Dm + (size_t)threadIdx.x * 4;
    *(uint2*)(g_hi + off) = make_uint2(h01, h23);
    *(uint2*)(g_lo + off) = make_uint2(l01, l23);
}

// Plain fp32 gather (fallback path)
__global__ __launch_bounds__(256)
void gather_rows(const float* __restrict__ h, const int* __restrict__ span,
                 float* __restrict__ gs, float* __restrict__ ge)
{
    const int row = blockIdx.x, which = blockIdx.y;
    const int b = row >> 6;
    const int idx = span[row * 2 + which];
    const float4* src = (const float4*)(h + ((size_t)b * Lseq + idx) * Dm);
    float4* dst = (float4*)((which ? ge : gs) + (size_t)row * Dm);
    dst[threadIdx.x] = src[threadIdx.x];
}

// ---------------------------------------------------------------------------
// Batched weight transpose+split: W[k][n] fp32 -> Wt_hi/lo[n][k] bf16.
// ---------------------------------------------------------------------------
struct TransJobs {
    const float* src[8];
    u16* dh[8];
    u16* dl[8];
    int K[8], N[8], tiles[8];
};

__global__ __launch_bounds__(256)
void transpose_split(TransJobs J)
{
    __shared__ float T[64][65];
    int b = blockIdx.x, j = 0;
    while (b >= J.tiles[j]) { b -= J.tiles[j]; ++j; }
    const float* src = J.src[j];
    const int K = J.K[j], N = J.N[j];
    const int tk = K >> 6;
    const int k0 = (b % tk) * 64, n0 = (b / tk) * 64;
    const int t = threadIdx.x, c = t & 63, r4 = t >> 6;
#pragma unroll
    for (int s = 0; s < 16; ++s) {
        int r = r4 * 16 + s;
        T[r][c] = src[(size_t)(k0 + r) * N + n0 + c];
    }
    __syncthreads();
    u16* dh = J.dh[j];
    u16* dl = J.dl[j];
#pragma unroll
    for (int s = 0; s < 16; ++s) {
        int n = r4 * 16 + s;
        float v = T[c][n];
        u32 hv = f2bf(v);
        dh[(size_t)(n0 + n) * K + k0 + c] = (u16)hv;
        if (dl) dl[(size_t)(n0 + n) * K + k0 + c] = (u16)f2bf(v - bf2f(hv));
    }
}

// ---------------------------------------------------------------------------
// Split-bf16 MFMA GEMM: C = act(A @ W + bias), A as hi/lo bf16 [M][K],
// W pre-transposed+split Wt_hi/lo[n][k]. Tile 64x64, K-step 32, 4 waves,
// wave w owns rows [w*16, w*16+16). 3 MFMAs per tile pair (hi*hi+lo*hi+hi*lo).
// ---------------------------------------------------------------------------
struct GemmP {
    const u16 *ah0, *ah1, *al0, *al1;
    const u16 *wh0, *wh1, *wl0, *wl1;
    const float *b0, *b1;
    float *of0, *of1;
    u16 *oh0, *oh1, *ol0, *ol1;
    int K, ldc, coloff1;
};

template<bool RELU, bool BIAS, bool SPLIT_OUT>
__global__ __launch_bounds__(256)
void gemm_split(GemmP P)
{
    __shared__ __align__(16) u16 As_h[64 * 32];
    __shared__ __align__(16) u16 As_l[64 * 32];
    __shared__ __align__(16) u16 Bs_h[64 * 32];
    __shared__ __align__(16) u16 Bs_l[64 * 32];

    const int tid = threadIdx.x, w = tid >> 6, l = tid & 63;
    const int lr = l & 15, lq = l >> 4;
    const int z = blockIdx.z;
    const int m0 = blockIdx.x * 64, n0 = blockIdx.y * 64;
    const int K = P.K;

    const u16* ah = z ? P.ah1 : P.ah0;
    const u16* al = z ? P.al1 : P.al0;
    const u16* wh = z ? P.wh1 : P.wh0;
    const u16* wl = z ? P.wl1 : P.wl0;

    // Each wave stages one 64x32 bf16 tile (4 KB) via 4 global_load_lds.
    const u16* src; u16* ldst;
    if      (w == 0) { src = ah + (size_t)m0 * K; ldst = As_h; }
    else if (w == 1) { src = al + (size_t)m0 * K; ldst = As_l; }
    else if (w == 2) { src = wh + (size_t)n0 * K; ldst = Bs_h; }
    else             { src = wl + (size_t)n0 * K; ldst = Bs_l; }
    const u16* sl = src + (size_t)(l >> 2) * K + (size_t)(l & 3) * 8;

    floatx4 acc[4];
#pragma unroll
    for (int nt = 0; nt < 4; ++nt) acc[nt] = (floatx4){0.f, 0.f, 0.f, 0.f};

    for (int k0 = 0; k0 < K; k0 += 32) {
        __syncthreads();
#pragma unroll
        for (int i = 0; i < 4; ++i)
            __builtin_amdgcn_global_load_lds(
                (const __attribute__((address_space(1))) u32*)(sl + (size_t)i * 16 * K + k0),
                (__attribute__((address_space(3))) u32*)(ldst + i * 512), 16, 0, 0);
        __syncthreads();

        const int ar = (w * 16 + lr) * 32 + lq * 8;
        short8 fah = *(const short8*)&As_h[ar];
        short8 fal = *(const short8*)&As_l[ar];
#pragma unroll
        for (int nt = 0; nt < 4; ++nt) {
            const int brd = (nt * 16 + lr) * 32 + lq * 8;
            short8 fbh = *(const short8*)&Bs_h[brd];
            short8 fbl = *(const short8*)&Bs_l[brd];
            acc[nt] = __builtin_amdgcn_mfma_f32_16x16x32_bf16(fah, fbh, acc[nt], 0, 0, 0);
            acc[nt] = __builtin_amdgcn_mfma_f32_16x16x32_bf16(fal, fbh, acc[nt], 0, 0, 0);
            acc[nt] = __builtin_amdgcn_mfma_f32_16x16x32_bf16(fah, fbl, acc[nt], 0, 0, 0);
        }
    }

    const float* bias = z ? P.b1 : P.b0;
    const int colb = n0 + (z ? P.coloff1 : 0);
    float bv[4];
    if (BIAS) {
#pragma unroll
        for (int nt = 0; nt < 4; ++nt) bv[nt] = bias[n0 + nt * 16 + lr];
    }
#pragma unroll
    for (int nt = 0; nt < 4; ++nt) {
#pragma unroll
        for (int r = 0; r < 4; ++r) {
            float x = acc[nt][r];
            if (BIAS) x += bv[nt];
            if (RELU) x = fmaxf(x, 0.f);
            const int m = m0 + w * 16 + lq * 4 + r;
            const size_t oidx = (size_t)m * P.ldc + colb + nt * 16 + lr;
            if (SPLIT_OUT) {
                u16* oh = z ? P.oh1 : P.oh0;
                u16* ol = z ? P.ol1 : P.ol0;
                u32 hv = f2bf(x);
                oh[oidx] = (u16)hv;
                ol[oidx] = (u16)f2bf(x - bf2f(hv));
            } else {
                float* of = z ? P.of1 : P.of0;
                of[oidx] = x;
            }
        }
    }
}

// ---------------------------------------------------------------------------
// fp32 GEMM fallback (round-1) for small layers if ws is too small.
// ---------------------------------------------------------------------------
template<bool RELU, bool BIAS>
__global__ __launch_bounds__(256)
void gemm_f32(const float* __restrict__ A, int lda,
              const float* __restrict__ W, int ldw,
              const float* __restrict__ bias,
              float* __restrict__ C, int ldc, int K)
{
    __shared__ float As[16][64];
    __shared__ float Ws[16][64];
    const int tid = threadIdx.x;
    const int tx = tid & 15, ty = tid >> 4;
    const int m0 = blockIdx.x * 64, n0 = blockIdx.y * 64;
    const int la_c = tid & 15, la_r = tid >> 4;
    const int lw_n = tid & 63, lw_k = tid >> 6;
    float acc[4][4] = {};
    for (int k0 = 0; k0 < K; k0 += 16) {
#pragma unroll
        for (int s = 0; s < 4; ++s) {
            int m = la_r + 16 * s;
            As[la_c][m] = A[(size_t)(m0 + m) * lda + k0 + la_c];
        }
#pragma unroll
        for (int s = 0; s < 4; ++s) {
            int k = lw_k + 4 * s;
            Ws[k][lw_n] = W[(size_t)(k0 + k) * ldw + n0 + lw_n];
        }
        __syncthreads();
#pragma unroll
        for (int kk = 0; kk < 16; ++kk) {
            float a4[4], w4[4];
            *(float4*)a4 = *(const float4*)&As[kk][ty * 4];
            *(float4*)w4 = *(const float4*)&Ws[kk][tx * 4];
#pragma unroll
            for (int i = 0; i < 4; ++i)
#pragma unroll
                for (int j = 0; j < 4; ++j)
                    acc[i][j] = fmaf(a4[i], w4[j], acc[i][j]);
        }
        __syncthreads();
    }
#pragma unroll
    for (int i = 0; i < 4; ++i) {
        float4 v; float* vp = (float*)&v;
#pragma unroll
        for (int j = 0; j < 4; ++j) {
            float x = acc[i][j];
            if (BIAS) x += bias[n0 + tx * 4 + j];
            if (RELU) x = fmaxf(x, 0.f);
            vp[j] = x;
        }
        *(float4*)&C[(size_t)(m0 + ty * 4 + i) * ldc + n0 + tx * 4] = v;
    }
}

// ---------------------------------------------------------------------------
// Final GEMM via bf16 MFMA; hidden = relu(hi ⊕ hj + br1) built on the fly.
// Conflict-free A-tile stores: each ds_write_b128 instr covers a contiguous
// wave-wide 1024 B (lane l -> row w*32+i*16+(l>>2), chunk l&3).
// ---------------------------------------------------------------------------
__global__ __launch_bounds__(256, 3)
void big_mfma(const float* __restrict__ hi, const float* __restrict__ hj,
              const float* __restrict__ br1, const u16* __restrict__ Wt,
              const float* __restrict__ br2, float* __restrict__ out)
{
    __shared__ float hiP[2][D2];                     // 16 KB
    __shared__ __align__(16) u16 Asb[128 * 32];      // 8 KB
    __shared__ __align__(16) u16 Bsb[128 * 32];      // 8 KB

    const int tid = threadIdx.x;
    const int p = blockIdx.x, n0 = blockIdx.y * 128;
    const int b = p >> 5, bi0 = p * 2;

    // hiP = hi(+pair) + br1
    {
        const float4* h0 = (const float4*)(hi + (size_t)bi0 * D2);
        const float4* h1 = (const float4*)(hi + (size_t)(bi0 + 1) * D2);
        const float4* br = (const float4*)br1;
        float4* d0 = (float4*)hiP[0];
        float4* d1 = (float4*)hiP[1];
        for (int v = tid; v < 512; v += 256) {
            float4 bb = br[v];
            float4 a = h0[v];
            a.x += bb.x; a.y += bb.y; a.z += bb.z; a.w += bb.w;
            d0[v] = a;
            float4 c = h1[v];
            c.x += bb.x; c.y += bb.y; c.z += bb.z; c.w += bb.w;
            d1[v] = c;
        }
    }

    const int w = tid >> 6, l = tid & 63;
    const int wm = w & 1, wn = w >> 1;
    const int lr = l & 15, lq = l >> 4;

    // A-build mapping: two rows per thread, one 16B chunk each
    const int c4 = l & 3;
    const int r0 = w * 32 + (l >> 2);
    const int r1 = r0 + 16;
    const int sel0 = r0 >> 6, j0 = r0 & 63;
    const int sel1 = r1 >> 6, j1 = r1 & 63;
    const float* hj0 = hj + ((size_t)b * 64 + j0) * D2 + c4 * 8;
    const float* hj1 = hj + ((size_t)b * 64 + j1) * D2 + c4 * 8;

    floatx4 acc[4][4];
#pragma unroll
    for (int mt = 0; mt < 4; ++mt)
#pragma unroll
        for (int nt = 0; nt < 4; ++nt)
            acc[mt][nt] = (floatx4){0.f, 0.f, 0.f, 0.f};

    for (int k0 = 0; k0 < D2; k0 += 32) {
        __syncthreads();

        // ---- A tile: relu(hi' + hj) -> bf16, conflict-free stores ----
        {
            float4 a0 = *(const float4*)(hj0 + k0);
            float4 a1 = *(const float4*)(hj0 + k0 + 4);
            float4 h0 = *(const float4*)&hiP[sel0][k0 + c4 * 8];
            float4 h1 = *(const float4*)&hiP[sel0][k0 + c4 * 8 + 4];
            u32 u0 = pk2(fmaxf(a0.x + h0.x, 0.f), fmaxf(a0.y + h0.y, 0.f));
            u32 u1 = pk2(fmaxf(a0.z + h0.z, 0.f), fmaxf(a0.w + h0.w, 0.f));
            u32 u2 = pk2(fmaxf(a1.x + h1.x, 0.f), fmaxf(a1.y + h1.y, 0.f));
            u32 u3 = pk2(fmaxf(a1.z + h1.z, 0.f), fmaxf(a1.w + h1.w, 0.f));
            *(uint4*)&Asb[r0 * 32 + c4 * 8] = make_uint4(u0, u1, u2, u3);

            float4 b0 = *(const float4*)(hj1 + k0);
            float4 b1 = *(const float4*)(hj1 + k0 + 4);
            float4 g0 = *(const float4*)&hiP[sel1][k0 + c4 * 8];
            float4 g1 = *(const float4*)&hiP[sel1][k0 + c4 * 8 + 4];
            u32 v0 = pk2(fmaxf(b0.x + g0.x, 0.f), fmaxf(b0.y + g0.y, 0.f));
            u32 v1 = pk2(fmaxf(b0.z + g0.z, 0.f), fmaxf(b0.w + g0.w, 0.f));
            u32 v2 = pk2(fmaxf(b1.x + g1.x, 0.f), fmaxf(b1.y + g1.y, 0.f));
            u32 v3 = pk2(fmaxf(b1.z + g1.z, 0.f), fmaxf(b1.w + g1.w, 0.f));
            *(uint4*)&Asb[r1 * 32 + c4 * 8] = make_uint4(v0, v1, v2, v3);
        }

        // ---- B tile: async bf16 stage ----
#pragma unroll
        for (int c = 0; c < 2; ++c) {
            const u16* g = Wt + (size_t)(n0 + w * 32 + c * 16 + (l >> 2)) * D2
                              + k0 + (l & 3) * 8;
            u16* lp = Bsb + (w * 2048 + c * 1024) / 2;
            __builtin_amdgcn_global_load_lds(
                (const __attribute__((address_space(1))) u32*)g,
                (__attribute__((address_space(3))) u32*)lp, 16, 0, 0);
        }

        __syncthreads();

        // ---- fragments + MFMA ----
        short8 af[4], bfr[4];
#pragma unroll
        for (int mt = 0; mt < 4; ++mt)
            af[mt] = *(const short8*)&Asb[(wm * 64 + mt * 16 + lr) * 32 + lq * 8];
#pragma unroll
        for (int nt = 0; nt < 4; ++nt)
            bfr[nt] = *(const short8*)&Bsb[(wn * 64 + nt * 16 + lr) * 32 + lq * 8];
#pragma unroll
        for (int mt = 0; mt < 4; ++mt)
#pragma unroll
            for (int nt = 0; nt < 4; ++nt)
                acc[mt][nt] = __builtin_amdgcn_mfma_f32_16x16x32_bf16(
                    af[mt], bfr[nt], acc[mt][nt], 0, 0, 0);
    }

    // ---- epilogue ----
    float bias[4];
#pragma unroll
    for (int nt = 0; nt < 4; ++nt)
        bias[nt] = br2[n0 + wn * 64 + nt * 16 + lr];

#pragma unroll
    for (int mt = 0; mt < 4; ++mt) {
        const int mbase = wm * 64 + mt * 16 + lq * 4;
#pragma unroll
        for (int r = 0; r < 4; ++r) {
            const int mm = mbase + r;
            const int sel = mm >> 6, j = mm & 63;
            float* orow = out + (((size_t)(bi0 + sel) * 64 + j) * Dm) + n0 + wn * 64;
#pragma unroll
            for (int nt = 0; nt < 4; ++nt)
                orow[nt * 16 + lr] = acc[mt][nt][r] + bias[nt];
        }
    }
}

// ---------------------------------------------------------------------------
extern "C" void kernel_launch(void* const* d_in, const int* in_sizes, int n_in,
                              void* d_out, int out_size, void* d_ws, size_t ws_size,
                              hipStream_t stream) {
    const float* h    = (const float*)d_in[0];
    const int*   span = (const int*)  d_in[1];
    const float* Ws1  = (const float*)d_in[2];
    const float* bs1  = (const float*)d_in[3];
    const float* Ws2  = (const float*)d_in[4];
    const float* bs2  = (const float*)d_in[5];
    const float* We1  = (const float*)d_in[6];
    const float* be1  = (const float*)d_in[7];
    const float* We2  = (const float*)d_in[8];
    const float* be2  = (const float*)d_in[9];
    const float* Wo   = (const float*)d_in[10];
    const float* bo   = (const float*)d_in[11];
    const float* Wr1  = (const float*)d_in[12];
    const float* br1  = (const float*)d_in[13];
    const float* Wr2  = (const float*)d_in[14];
    const float* br2  = (const float*)d_in[15];
    float* out = (float*)d_out;

    dim3 blk(256);
    const size_t REQUIRED = (size_t)120 << 20;

    if (ws_size >= REQUIRED) {
        // ---------------- split-bf16 MFMA path ----------------
        char* W = (char*)d_ws;
        size_t off = 0;
        auto alloc = [&](size_t bytes) { char* q = W + off; off += bytes; return q; };

        u16* W1t_h = (u16*)alloc((size_t)2 * 2048 * 1024 * 2);
        u16* W1t_l = (u16*)alloc((size_t)2 * 2048 * 1024 * 2);
        u16* W2t_h = (u16*)alloc((size_t)2 * 1024 * 2048 * 2);
        u16* W2t_l = (u16*)alloc((size_t)2 * 1024 * 2048 * 2);
        u16* Wot_h = (u16*)alloc((size_t)2048 * 2048 * 2);
        u16* Wot_l = (u16*)alloc((size_t)2048 * 2048 * 2);
        u16* Wr1t_h = (u16*)alloc((size_t)2 * 2048 * 2048 * 2);
        u16* Wr1t_l = (u16*)alloc((size_t)2 * 2048 * 2048 * 2);
        u16* Wr2t_h = (u16*)alloc((size_t)1024 * 2048 * 2);
        u16* gs_h  = (u16*)alloc((size_t)2 * 512 * 1024 * 2);
        u16* gs_l  = (u16*)alloc((size_t)2 * 512 * 1024 * 2);
        u16* t1_h  = (u16*)alloc((size_t)2 * 512 * 2048 * 2);
        u16* t1_l  = (u16*)alloc((size_t)2 * 512 * 2048 * 2);
        u16* cat_h = (u16*)alloc((size_t)512 * 2048 * 2);
        u16* cat_l = (u16*)alloc((size_t)512 * 2048 * 2);
        u16* ent_h = (u16*)alloc((size_t)512 * 2048 * 2);
        u16* ent_l = (u16*)alloc((size_t)512 * 2048 * 2);
        float* hif = (float*)alloc((size_t)512 * 2048 * 4);
        float* hjf = (float*)alloc((size_t)512 * 2048 * 4);

        TransJobs J;
        J.src[0] = Ws1;  J.dh[0] = W1t_h;                J.dl[0] = W1t_l;                J.K[0] = 1024; J.N[0] = 2048; J.tiles[0] = 512;
        J.src[1] = We1;  J.dh[1] = W1t_h + 2048 * 1024;  J.dl[1] = W1t_l + 2048 * 1024;  J.K[1] = 1024; J.N[1] = 2048; J.tiles[1] = 512;
        J.src[2] = Ws2;  J.dh[2] = W2t_h;                J.dl[2] = W2t_l;                J.K[2] = 2048; J.N[2] = 1024; J.tiles[2] = 512;
        J.src[3] = We2;  J.dh[3] = W2t_h + 1024 * 2048;  J.dl[3] = W2t_l + 1024 * 2048;  J.K[3] = 2048; J.N[3] = 1024; J.tiles[3] = 512;
        J.src[4] = Wo;   J.dh[4] = Wot_h;                J.dl[4] = Wot_l;                J.K[4] = 2048; J.N[4] = 2048; J.tiles[4] = 1024;
        J.src[5] = Wr1;  J.dh[5] = Wr1t_h;               J.dl[5] = Wr1t_l;               J.K[5] = 2048; J.N[5] = 2048; J.tiles[5] = 1024;
        J.src[6] = Wr1 + (size_t)2048 * 2048;
                         J.dh[6] = Wr1t_h + (size_t)2048 * 2048; J.dl[6] = Wr1t_l + (size_t)2048 * 2048;
                                                                          J.K[6] = 2048; J.N[6] = 2048; J.tiles[6] = 1024;
        J.src[7] = Wr2;  J.dh[7] = Wr2t_h;               J.dl[7] = nullptr;              J.K[7] = 2048; J.N[7] = 1024; J.tiles[7] = 512;
        transpose_split<<<dim3(5632), blk, 0, stream>>>(J);

        gather_split<<<dim3(512, 2), blk, 0, stream>>>(h, span, gs_h, gs_l);

        GemmP p1 = {};
        p1.ah0 = gs_h; p1.ah1 = gs_h + 512 * 1024;
        p1.al0 = gs_l; p1.al1 = gs_l + 512 * 1024;
        p1.wh0 = W1t_h; p1.wh1 = W1t_h + 2048 * 1024;
        p1.wl0 = W1t_l; p1.wl1 = W1t_l + 2048 * 1024;
        p1.b0 = bs1; p1.b1 = be1;
        p1.oh0 = t1_h; p1.oh1 = t1_h + 512 * 2048;
        p1.ol0 = t1_l; p1.ol1 = t1_l + 512 * 2048;
        p1.K = 1024; p1.ldc = 2048; p1.coloff1 = 0;
        gemm_split<true, true, true><<<dim3(8, 32, 2), blk, 0, stream>>>(p1);

        GemmP p2 = {};
        p2.ah0 = t1_h; p2.ah1 = t1_h + 512 * 2048;
        p2.al0 = t1_l; p2.al1 = t1_l + 512 * 2048;
        p2.wh0 = W2t_h; p2.wh1 = W2t_h + 1024 * 2048;
        p2.wl0 = W2t_l; p2.wl1 = W2t_l + 1024 * 2048;
        p2.b0 = bs2; p2.b1 = be2;
        p2.oh0 = cat_h; p2.oh1 = cat_h;
        p2.ol0 = cat_l; p2.ol1 = cat_l;
        p2.K = 2048; p2.ldc = 2048; p2.coloff1 = 1024;
        gemm_split<true, true, true><<<dim3(8, 16, 2), blk, 0, stream>>>(p2);

        GemmP p3 = {};
        p3.ah0 = cat_h; p3.al0 = cat_l;
        p3.wh0 = Wot_h; p3.wl0 = Wot_l;
        p3.b0 = bo;
        p3.oh0 = ent_h; p3.ol0 = ent_l;
        p3.K = 2048; p3.ldc = 2048; p3.coloff1 = 0;
        gemm_split<false, true, true><<<dim3(8, 32, 1), blk, 0, stream>>>(p3);

        GemmP p4 = {};
        p4.ah0 = ent_h; p4.ah1 = ent_h;
        p4.al0 = ent_l; p4.al1 = ent_l;
        p4.wh0 = Wr1t_h; p4.wh1 = Wr1t_h + (size_t)2048 * 2048;
        p4.wl0 = Wr1t_l; p4.wl1 = Wr1t_l + (size_t)2048 * 2048;
        p4.of0 = hif; p4.of1 = hjf;
        p4.K = 2048; p4.ldc = 2048; p4.coloff1 = 0;
        gemm_split<false, false, false><<<dim3(8, 32, 2), blk, 0, stream>>>(p4);

        big_mfma<<<dim3(256, 8), blk, 0, stream>>>(hif, hjf, br1, Wr2t_h, br2, out);
    } else {
        // ---------------- fp32 fallback (round-1 structure) ----------------
        u16* Wt = (u16*)d_ws;                               // 4 MB
        float* ws  = (float*)((char*)d_ws + (size_t)Dm * D2 * 2);
        float* gs  = ws;
        float* ge  = gs  + 512 * Dm;
        float* t1  = ge  + 512 * Dm;
        float* cat = t1  + 512 * D2;
        float* ent = cat + 512 * D2;
        float* hi  = ent + 512 * D2;
        float* hj  = hi  + 512 * D2;

        TransJobs J = {};
        J.src[0] = Wr2; J.dh[0] = Wt; J.dl[0] = nullptr;
        J.K[0] = 2048; J.N[0] = 1024; J.tiles[0] = 512;
        transpose_split<<<dim3(512), blk, 0, stream>>>(J);

        gather_rows<<<dim3(512, 2), blk, 0, stream>>>(h, span, gs, ge);
        gemm_f32<true,  true><<<dim3(8, 32), blk, 0, stream>>>(gs, Dm, Ws1, D2, bs1, t1, D2, Dm);
        gemm_f32<true,  true><<<dim3(8, 16), blk, 0, stream>>>(t1, D2, Ws2, Dm, bs2, cat, D2, D2);
        gemm_f32<true,  true><<<dim3(8, 32), blk, 0, stream>>>(ge, Dm, We1, D2, be1, t1, D2, Dm);
        gemm_f32<true,  true><<<dim3(8, 16), blk, 0, stream>>>(t1, D2, We2, Dm, be2, cat + Dm, D2, D2);
        gemm_f32<false, true><<<dim3(8, 32), blk, 0, stream>>>(cat, D2, Wo, D2, bo, ent, D2, D2);
        gemm_f32<false, false><<<dim3(8, 32), blk, 0, stream>>>(ent, D2, Wr1, D2, nullptr, hi, D2, D2);
        gemm_f32<false, false><<<dim3(8, 32), blk, 0, stream>>>(ent, D2, Wr1 + (size_t)D2 * D2, D2, nullptr, hj, D2, D2);
        big_mfma<<<dim3(256, 8), blk, 0, stream>>>(hi, hj, br1, Wt, br2, out);
    }
}